// Round 10
// baseline (332.424 us; speedup 1.0000x reference)
//
#include <hip/hip_runtime.h>
#include <math.h>

#define TT   16
#define BATCH 8
#define HH   64
#define WW   64
#define HWSZ 4096
#define HID  32
#define CT_STRIDE 68

typedef __bf16 bf16x8 __attribute__((ext_vector_type(8)));
typedef float  f32x16 __attribute__((ext_vector_type(16)));
typedef unsigned short u16;
typedef unsigned int   u32;
typedef unsigned long long u64;
typedef u32 u32x4 __attribute__((ext_vector_type(4)));

__device__ __forceinline__ u16 f2bf(float f) {
    union { float f; u32 u; } v; v.f = f;
    u32 r = v.u + 0x7FFF + ((v.u >> 16) & 1);   // RNE
    return (u16)(r >> 16);
}

// ---- merged prep: x -> pixel-major bf16; W0/W1 -> 32x32 MFMA B-frag order ----
// wf layout: [tap(9)][kc16(4)][T(4)][lane(64)] x 16B. n-tile T: khalf = T>>1,
// gate-pair = T&1; within-tile col: gate parity = col>>4, hid16 = col&15.
__device__ __forceinline__ void prep_w32(const float* __restrict__ W,
                                         u16* __restrict__ wf, int cinl, int idx) {
    const int lane = idx & 63, T = (idx >> 6) & 3, kc16 = (idx >> 8) & 3, tap = idx >> 10;
    const int col  = lane & 31;
    const int gate = (T & 1) * 2 + (col >> 4);
    const int hid  = (T >> 1) * 16 + (col & 15);
    const int cho  = gate * HID + hid;
    const int cb   = kc16 * 16 + (lane >> 5) * 8;
    u16 o[8];
#pragma unroll
    for (int j = 0; j < 8; ++j) {
        const int cin = cb + j;
        o[j] = (cin < cinl) ? f2bf(W[((size_t)cho * cinl + cin) * 9 + tap]) : (u16)0;
    }
    ((uint4*)wf)[idx] = *(uint4*)&o[0];
}

__global__ __launch_bounds__(256)
void prep_all(const float* __restrict__ x, u16* __restrict__ xbf,
              const float* __restrict__ W0, u16* __restrict__ wf0,
              const float* __restrict__ W1, u16* __restrict__ wf1) {
    const int bid = blockIdx.x, tid = threadIdx.x;
    if (bid < 2048) {
        const int p = bid * 256 + tid;           // (t*8+b)*4096 + pix
        const int tb = p >> 12, pix = p & 4095;
        const float* src = x + ((size_t)tb * 16) * HWSZ + pix;
        u16 o[16];
#pragma unroll
        for (int c = 0; c < 16; ++c) o[c] = f2bf(src[(size_t)c * HWSZ]);
        uint4* dst = (uint4*)(xbf + (size_t)p * 16);
        dst[0] = *(uint4*)&o[0];
        dst[1] = *(uint4*)&o[8];
    } else if (bid < 2084) {
        prep_w32(W0, wf0, 48, (bid - 2048) * 256 + tid);
    } else {
        prep_w32(W1, wf1, 64, (bid - 2084) * 256 + tid);
    }
}

// ---- fused ConvLSTM step v9: 32x32x16 MFMA, exact K for layer0 ----
// Per layer-half: 256 blocks; blk -> b = blk>>5, y0 = (blk&31)*2 (2 output rows).
// Block = 4 waves: wave w -> row (w>>1), khalf (w&1). Wave tile M=64 px x N=64 ch
// (2 m-tiles of 32 px x 2 gate-pair n-tiles for 16 hid channels).
// NKC = K16 cells (3 for layer0 K=48 exact, 4 for layer1 K=64).
template<int NKC, int XCH>
__device__ __forceinline__ void conv_step(
    const u16* __restrict__ srcX,                   // pixel-major bf16 [B*4096][XCH]
    const u16* __restrict__ srcH,                   // pixel-major bf16 [B*4096][32]
    const uint4* __restrict__ wf,                   // [9][4][4][64] x 16B
    const float* __restrict__ bias,                 // [128] gate-major
    float* __restrict__ cbuf,                       // [B,32,H,W] running c (in/out)
    float* __restrict__ hout, float* __restrict__ hT,
    u16* __restrict__ hbfo,
    int t0, int blk, uint4* lds4, float* ctile)
{
    constexpr int NCH = (XCH + 32) / 8;    // staged 8-cin chunks: 6 or 8
    constexpr int NG  = 9 * NKC;           // K-groups: 27 or 36

    const int tid = threadIdx.x;
    const int y0 = (blk & 31) * 2;
    const int b  = blk >> 5;

    // ---- stage 4 rows x 66 px x NCH*8 cin (16B chunks), XOR-swizzled ----
    for (int q = tid; q < 264 * NCH; q += 256) {
        const int c8 = q % NCH;
        const int pr = q / NCH;         // 0..263
        const int px = pr % 66;
        const int r  = pr / 66;         // 0..3  (gy = y0-1+r)
        const int gy = y0 - 1 + r;
        const int gx = px - 1;
        uint4 v = {0u, 0u, 0u, 0u};
        if (gy >= 0 && gy < HH && gx >= 0 && gx < WW) {
            const int pix = b * HWSZ + gy * WW + gx;
            const int cin8 = c8 * 8;
            if (cin8 < XCH) {
                v = *(const uint4*)(srcX + (size_t)pix * XCH + cin8);
            } else {
                if (!t0) v = *(const uint4*)(srcH + (size_t)pix * 32 + (cin8 - XCH));
            }
        }
        lds4[(pr * 8 + c8) ^ (px & 7)] = v;
    }

    // ---- coalesced c-tile load: cbuf channel-major -> ctile[(yy*32+c)][p] ----
    const int fr  = tid >> 2;          // 0..63
    const int fyy = fr >> 5, fc = fr & 31;
    const size_t gflat = ((size_t)(b * HID + fc) * HH + (y0 + fyy)) * WW;
    if (!t0) {
#pragma unroll
        for (int j = 0; j < 4; ++j) {
            const int q = j * 4 + (tid & 3);
            *(uint4*)(ctile + fr * CT_STRIDE + q * 4) =
                *(const uint4*)(cbuf + gflat + q * 4);
        }
    }
    __syncthreads();

    const int lane  = tid & 63;
    const int w     = tid >> 6;
    const int l31   = lane & 31, khi = lane >> 5;
    const int l15   = lane & 15;
    const int p     = l31 >> 4;         // gate parity this lane holds
    const int khalf = w & 1;
    const int wrow  = w >> 1;

    float bv[2];
#pragma unroll
    for (int n = 0; n < 2; ++n)
        bv[n] = bias[(2 * n + p) * HID + khalf * 16 + l15];

    f32x16 acc[2][2];
#pragma unroll
    for (int m = 0; m < 2; ++m)
#pragma unroll
        for (int n = 0; n < 2; ++n)
#pragma unroll
            for (int j = 0; j < 16; ++j) acc[m][n][j] = bv[n];

    // group g: tap = g/NKC, kc16 = g%NKC
    auto LOADA = [&](bf16x8* dst, int g) {
        const int tap = g / NKC, kc = g % NKC;
        const int sr = wrow + tap / 3;
        const int dx = tap % 3 - 1;
        const int c8 = kc * 2 + khi;
#pragma unroll
        for (int m = 0; m < 2; ++m) {
            const int pxt = 1 + m * 32 + l31 + dx;
            dst[m] = __builtin_bit_cast(bf16x8,
                     lds4[(((sr * 66 + pxt) * 8) + c8) ^ (pxt & 7)]);
        }
    };
    auto LOADB = [&](bf16x8* dst, int g) {
        const int tap = g / NKC, kc = g % NKC;
#pragma unroll
        for (int n = 0; n < 2; ++n)
            dst[n] = __builtin_bit_cast(bf16x8,
                     wf[(((tap * 4 + kc) * 4) + (khalf * 2 + n)) * 64 + lane]);
    };
    auto MFMAG = [&](const bf16x8* a, const bf16x8* bw) {
#pragma unroll
        for (int n = 0; n < 2; ++n)
#pragma unroll
            for (int m = 0; m < 2; ++m)
                acc[m][n] = __builtin_amdgcn_mfma_f32_32x32x16_bf16(
                                a[m], bw[n], acc[m][n], 0, 0, 0);
    };

    bf16x8 a0[2], a1[2], a2[2], b0[2], b1[2], b2[2];
    LOADA(a0, 0); LOADB(b0, 0);
    LOADA(a1, 1); LOADB(b1, 1);
    LOADA(a2, 2); LOADB(b2, 2);
#pragma unroll
    for (int g = 0; g < NG; g += 3) {
        MFMAG(a0, b0);
        if (g + 3 < NG) { LOADA(a0, g + 3); LOADB(b0, g + 3); }
        MFMAG(a1, b1);
        if (g + 4 < NG) { LOADA(a1, g + 4); LOADB(b1, g + 4); }
        MFMAG(a2, b2);
        if (g + 5 < NG) { LOADA(a2, g + 5); LOADB(b2, g + 5); }
    }

    __syncthreads();                    // lds4 A-tile no longer needed
    float* htile = (float*)lds4;        // [64][CT_STRIDE] fp32

    // ---- LSTM epilogue: exchange gate pairs across lane^16, own m-tile = p ----
    // p0 lane holds (i,o) tiles, p1 holds (f,g). p0 owns m=0 pixels, p1 owns m=1.
    const int row = wrow * 32 + khalf * 16 + l15;   // transpose-tile row
#pragma unroll
    for (int r = 0; r < 16; ++r) {
        // send the tile the PARTNER owns (p0 sends m1, p1 sends m0)
        const float s0 = p ? acc[0][0][r] : acc[1][0][r];
        const float s1 = p ? acc[0][1][r] : acc[1][1][r];
        const float r0 = __shfl_xor(s0, 16);
        const float r1 = __shfl_xor(s1, 16);
        const float own0 = p ? acc[1][0][r] : acc[0][0][r];
        const float own1 = p ? acc[1][1][r] : acc[0][1][r];
        const float iv = p ? r0 : own0;
        const float fv = p ? own0 : r0;
        const float ov = p ? r1 : own1;
        const float gv = p ? own1 : r1;
        const int px = p * 32 + (r & 3) + 8 * (r >> 2) + 4 * khi;

        const float cp = t0 ? 0.f : ctile[row * CT_STRIDE + px];
        const float ig = __builtin_amdgcn_rcpf(1.f + __expf(-iv));
        const float fg = __builtin_amdgcn_rcpf(1.f + __expf(-fv));
        const float og = __builtin_amdgcn_rcpf(1.f + __expf(-ov));
        const float gg = 1.f - 2.f * __builtin_amdgcn_rcpf(1.f + __expf(2.f * gv));
        const float cn = fg * cp + ig * gg;
        const float hn = og * (1.f - 2.f * __builtin_amdgcn_rcpf(1.f + __expf(2.f * cn)));
        ctile[row * CT_STRIDE + px] = cn;
        htile[row * CT_STRIDE + px] = hn;
    }
    __syncthreads();

    // ---- flush 1: htile -> hseq[t] / hT (nt stores), ctile -> cbuf ----
#pragma unroll
    for (int j = 0; j < 4; ++j) {
        const int q = j * 4 + (tid & 3);
        const u32x4 hv = *(const u32x4*)(htile + fr * CT_STRIDE + q * 4);
        const uint4 cv = *(const uint4*)(ctile + fr * CT_STRIDE + q * 4);
        __builtin_nontemporal_store(hv, (u32x4*)(hout + gflat + q * 4));
        *(uint4*)(cbuf + gflat + q * 4) = cv;
        if (hT) __builtin_nontemporal_store(hv, (u32x4*)(hT + gflat + q * 4));
    }

    // ---- flush 2: htile -> hbf ping-pong, packed u64 coalesced stores ----
#pragma unroll
    for (int j = 0; j < 4; ++j) {
        const int idx = j * 256 + tid;       // 0..1023
        const int c4  = idx & 7;
        const int pxx = (idx >> 3) & 63;
        const int yy  = idx >> 9;
        u16 pk[4];
#pragma unroll
        for (int k = 0; k < 4; ++k)
            pk[k] = f2bf(htile[(yy * 32 + c4 * 4 + k) * CT_STRIDE + pxx]);
        const int pix = b * HWSZ + (y0 + yy) * WW + pxx;
        *(u64*)(hbfo + (size_t)pix * 32 + c4 * 4) = *(u64*)pk;
    }
}

__global__ __launch_bounds__(256, 2)
void fused_step(
    const u16* srcX0, const u16* srcH0, const uint4* wf0, const float* bias0,
    float* cbuf0, float* hout0, float* hT0, u16* hbfo0, int t00, int act0,
    const u16* srcX1, const u16* srcH1, const uint4* wf1, const float* bias1,
    float* cbuf1, float* hout1, float* hT1, u16* hbfo1, int t01, int act1)
{
    __shared__ uint4 lds4[2112];              // 33,792 B (A-tile, then htile)
    __shared__ float ctile[64 * CT_STRIDE];   // 17,408 B
    const int blk = blockIdx.x;
    if (blk < 256) {
        if (!act0) return;
        conv_step<3, 16>(srcX0, srcH0, wf0, bias0, cbuf0, hout0, hT0, hbfo0, t00, blk, lds4, ctile);
    } else {
        if (!act1) return;
        conv_step<4, 32>(srcX1, srcH1, wf1, bias1, cbuf1, hout1, hT1, hbfo1, t01, blk - 256, lds4, ctile);
    }
}

extern "C" void kernel_launch(void* const* d_in, const int* in_sizes, int n_in,
                              void* d_out, int out_size, void* d_ws, size_t ws_size,
                              hipStream_t stream) {
    const float* x  = (const float*)d_in[0];
    const float* W0 = (const float*)d_in[1];
    const float* b0 = (const float*)d_in[2];
    const float* W1 = (const float*)d_in[3];
    const float* b1 = (const float*)d_in[4];
    float* out = (float*)d_out;

    float* hseq0 = out;
    float* hseq1 = out + 16777216;
    float* h0T   = out + 33554432;
    float* c0T   = out + 34603008;   // running c, layer 0 (channel-major, in-place)
    float* h1T   = out + 35651584;
    float* c1T   = out + 36700160;   // running c, layer 1

    // ws: xbf 16,777,216 | wf0 147,456 | wf1 147,456 | hbf0[2] | hbf1[2]
    char* ws = (char*)d_ws;
    u16*  xbf = (u16*)ws;
    u16*  wf0 = (u16*)(ws + 16777216);
    u16*  wf1 = (u16*)(ws + 16777216 + 147456);
    u16*  hbf0[2] = { (u16*)(ws + 17072128), (u16*)(ws + 17072128 + 2097152) };
    u16*  hbf1[2] = { (u16*)(ws + 21266432), (u16*)(ws + 21266432 + 2097152) };

    prep_all<<<2120, 256, 0, stream>>>(x, xbf, W0, wf0, W1, wf1);

    const size_t hstep = (size_t)BATCH * HID * HWSZ;   // 1,048,576 floats
    const size_t xstep = (size_t)BATCH * HWSZ * 16;    // bf16 elems per t

    for (int d = 0; d <= TT; ++d) {
        const int t0 = (d < TT) ? d : TT - 1;      // clamped (inactive half)
        const int t1 = (d >= 1) ? d - 1 : 0;
        const int act0 = (d < TT), act1 = (d >= 1);
        fused_step<<<512, 256, 0, stream>>>(
            xbf + (size_t)t0 * xstep, hbf0[(t0 - 1) & 1],
            (const uint4*)wf0, b0, c0T,
            hseq0 + (size_t)t0 * hstep, (t0 == TT - 1 && act0) ? h0T : nullptr,
            hbf0[t0 & 1], (t0 == 0) ? 1 : 0, act0,
            hbf0[t1 & 1], hbf1[(t1 - 1) & 1],
            (const uint4*)wf1, b1, c1T,
            hseq1 + (size_t)t1 * hstep, (t1 == TT - 1 && act1) ? h1T : nullptr,
            hbf1[t1 & 1], (t1 == 0) ? 1 : 0, act1);
    }
}